// Round 1
// baseline (897.251 us; speedup 1.0000x reference)
//
#include <hip/hip_runtime.h>

// Problem constants
// B=1024, F=512, N=8
// inputs: vx[1024,512] ax[1024,512] W1[8,512,1024] b1[8,512] W2[8,512,512] b2[8,512]
//         conv1_w[512,512,3,3] conv1_b[512] conv2_w[512,512,3,3] conv2_b[512]
// out: [1024,512] f32

// ---------------------------------------------------------------------------
// Generic tiled fp32 GEMM:  C[M,N] = A[M,K] * B[N,K]^T  (NT), optional bias+relu,
// batched over blockIdx.z via strides. TILE = 16*MT, 256 threads, BK=16.
// ---------------------------------------------------------------------------
template<int MT, bool RELU, bool BIAS>
__global__ __launch_bounds__(256) void gemm_nt(
    const float* __restrict__ A, int lda, long sA,
    const float* __restrict__ Bm, int ldb, long sB,
    float* __restrict__ C, int ldc, long sC,
    const float* __restrict__ bias, long sBias,
    int K)
{
    constexpr int TILE = 16 * MT;
    __shared__ __align__(16) float As[16][TILE + 4];
    __shared__ __align__(16) float Bs[16][TILE + 4];
    const int z = blockIdx.z;
    A  += (long)z * sA;
    Bm += (long)z * sB;
    C  += (long)z * sC;
    const float* bp = BIAS ? (bias + (long)z * sBias) : nullptr;
    const int bm = blockIdx.y * TILE;
    const int bn = blockIdx.x * TILE;
    const int t  = threadIdx.x;
    const int tx = t & 15, ty = t >> 4;

    float acc[MT][MT] = {};

    for (int k0 = 0; k0 < K; k0 += 16) {
        #pragma unroll
        for (int i = 0; i < TILE / 64; ++i) {
            int s   = t + i * 256;          // slot over TILE rows x 4 k-groups
            int row = s >> 2;
            int kg  = (s & 3) << 2;
            float4 v = *(const float4*)(A  + (long)(bm + row) * lda + k0 + kg);
            As[kg + 0][row] = v.x; As[kg + 1][row] = v.y;
            As[kg + 2][row] = v.z; As[kg + 3][row] = v.w;
            float4 w = *(const float4*)(Bm + (long)(bn + row) * ldb + k0 + kg);
            Bs[kg + 0][row] = w.x; Bs[kg + 1][row] = w.y;
            Bs[kg + 2][row] = w.z; Bs[kg + 3][row] = w.w;
        }
        __syncthreads();
        #pragma unroll
        for (int kk = 0; kk < 16; ++kk) {
            float av[MT], bv[MT];
            #pragma unroll
            for (int i = 0; i < MT / 4; ++i) {
                float4 a = *(const float4*)&As[kk][ty * MT + i * 4];
                av[i*4+0] = a.x; av[i*4+1] = a.y; av[i*4+2] = a.z; av[i*4+3] = a.w;
                float4 b = *(const float4*)&Bs[kk][tx * MT + i * 4];
                bv[i*4+0] = b.x; bv[i*4+1] = b.y; bv[i*4+2] = b.z; bv[i*4+3] = b.w;
            }
            #pragma unroll
            for (int i = 0; i < MT; ++i)
                #pragma unroll
                for (int j = 0; j < MT; ++j)
                    acc[i][j] = fmaf(av[i], bv[j], acc[i][j]);
        }
        __syncthreads();
    }

    #pragma unroll
    for (int i = 0; i < MT; ++i) {
        long m = bm + ty * MT + i;
        #pragma unroll
        for (int j = 0; j < MT; ++j) {
            int n = bn + tx * MT + j;
            float v = acc[i][j];
            if (BIAS) v += bp[n];
            if (RELU) v = fmaxf(v, 0.f);
            C[m * ldc + n] = v;
        }
    }
}

// x = concat(vx, ax) -> [1024, 1024]
__global__ void concat_kernel(const float* __restrict__ vx,
                              const float* __restrict__ ax,
                              float* __restrict__ x)
{
    int i = blockIdx.x * 256 + threadIdx.x;     // 0 .. 524287  (b*512+c)
    int b = i >> 9, c = i & 511;
    x[((long)b << 10) + c]       = vx[i];
    x[((long)b << 10) + 512 + c] = ax[i];
}

// im2col for the width-collapsed conv1:
// A1[(b*8+i)][ki*512+c] = (0<=i+ki-1<8) ? vx[b,c]*att[b,i+ki-1,c] : 0
__global__ void im2col_kernel(const float* __restrict__ vx,
                              const float* __restrict__ att,
                              float* __restrict__ A1)
{
    int col = blockIdx.x * 256 + threadIdx.x;   // 0..1535
    int row = blockIdx.y;                       // 0..8191 (b*8+i)
    int b = row >> 3, i = row & 7;
    int ki = col >> 9, c = col & 511;
    int ip = i + ki - 1;
    float v = 0.f;
    if (ip >= 0 && ip < 8)
        v = vx[(b << 9) + c] * att[((long)b << 12) + (ip << 9) + c];
    A1[(long)row * 1536 + col] = v;
}

// Wcat[v*512+o][ki*512+c] = sum over allowed kj of conv1_w[o,c,ki,kj]
// v=0: kj in {1,2} (left col j=0), v=1: all kj (middle), v=2: kj in {0,1} (right)
__global__ void wcat_kernel(const float* __restrict__ w1c,
                            float* __restrict__ Wcat)
{
    int col = blockIdx.x * 256 + threadIdx.x;   // 0..1535 (ki*512+c)
    int row = blockIdx.y;                       // 0..1535 (v*512+o)
    int v = row >> 9, o = row & 511;
    int ki = col >> 9, c = col & 511;
    const float* w = w1c + ((long)(o * 512 + c) * 3 + ki) * 3;
    float s = w[1];
    if (v != 0) s += w[0];
    if (v != 2) s += w[2];
    Wcat[(long)row * 1536 + col] = s;
}

// maxpool over the 8x(3-variant) conv1 values + conv1 bias (commutes with max)
// P[b][o*4 + pi*2 + pj]
__global__ void pool_kernel(const float* __restrict__ Y1,
                            const float* __restrict__ c1b,
                            float* __restrict__ P)
{
    int idx = blockIdx.x * 256 + threadIdx.x;   // 0..524287 (b*512+o)
    int b = idx >> 9, o = idx & 511;
    const float* y = Y1 + (long)b * 8 * 1536 + o;
    float bias = c1b[o];
    float pv[2][2];
    #pragma unroll
    for (int pi = 0; pi < 2; ++pi) {
        float m0 = -3.402823466e38f, m1 = -3.402823466e38f;
        #pragma unroll
        for (int r = 0; r < 4; ++r) {
            int i = pi * 4 + r;
            float yl = y[i * 1536 + 0];
            float ym = y[i * 1536 + 512];
            float yr = y[i * 1536 + 1024];
            m0 = fmaxf(m0, fmaxf(yl, ym));
            m1 = fmaxf(m1, fmaxf(ym, yr));
        }
        pv[pi][0] = m0; pv[pi][1] = m1;
    }
    float* pp = P + ((long)b * 2048) + o * 4;
    pp[0] = pv[0][0] + bias; pp[1] = pv[0][1] + bias;
    pp[2] = pv[1][0] + bias; pp[3] = pv[1][1] + bias;
}

// conv2+mean folded: M2[o2][c*4+pi*2+pj] = 0.25 * sum of the 2x2 kernel taps
// ki in {pi, pi+1}, kj in {pj, pj+1}
__global__ void m2_kernel(const float* __restrict__ w2c,
                          float* __restrict__ M2)
{
    int col = blockIdx.x * 256 + threadIdx.x;   // 0..2047
    int o2  = blockIdx.y;                       // 0..511
    int c = col >> 2, pi = (col >> 1) & 1, pj = col & 1;
    const float* w = w2c + (long)(o2 * 512 + c) * 9;
    float s = w[pi * 3 + pj] + w[pi * 3 + pj + 1]
            + w[(pi + 1) * 3 + pj] + w[(pi + 1) * 3 + pj + 1];
    M2[(long)o2 * 2048 + col] = 0.25f * s;
}

extern "C" void kernel_launch(void* const* d_in, const int* in_sizes, int n_in,
                              void* d_out, int out_size, void* d_ws, size_t ws_size,
                              hipStream_t stream)
{
    const float* vx  = (const float*)d_in[0];
    const float* ax  = (const float*)d_in[1];
    const float* W1  = (const float*)d_in[2];
    const float* b1  = (const float*)d_in[3];
    const float* W2  = (const float*)d_in[4];
    const float* b2  = (const float*)d_in[5];
    const float* c1w = (const float*)d_in[6];
    const float* c1b = (const float*)d_in[7];
    const float* c2w = (const float*)d_in[8];
    const float* c2b = (const float*)d_in[9];
    float* out = (float*)d_out;
    float* ws  = (float*)d_ws;

    // workspace layout (floats); Y1 reuses X/H/ATT region (dead by then)
    float* X   = ws + 0;            // 1,048,576   [0,4MB)
    float* H   = ws + 1048576;      // 4,194,304   [4,20MB)
    float* ATT = ws + 5242880;      // 4,194,304   [20,36MB)
    float* A1  = ws + 9437184;      // 12,582,912  [36,84MB)
    float* Y1  = ws + 0;            // 12,582,912  [0,48MB)  overlap OK (stream-ordered)
    float* P   = ws + 22020096;     // 2,097,152   [84,92MB)
    float* WC  = ws + 24117248;     // 2,359,296   [92,101MB)
    float* M2  = ws + 26476544;     // 1,048,576   [101,105MB)

    // 1) x = concat(vx, ax)
    concat_kernel<<<2048, 256, 0, stream>>>(vx, ax, X);

    // 2) h = relu(x @ W1^T + b1): M=1024, N=4096, K=1024
    gemm_nt<8, true, true><<<dim3(32, 8, 1), 256, 0, stream>>>(
        X, 1024, 0, W1, 1024, 0, H, 4096, 0, b1, 0, 1024);

    // 3) att = relu(h_n @ W2_n^T + b2_n), batched over n: M=1024, N=512, K=512
    gemm_nt<8, true, true><<<dim3(4, 8, 8), 256, 0, stream>>>(
        H, 4096, 512, W2, 512, 262144, ATT, 4096, 512, b2, 512, 512);

    // 4) im2col of va (vx*att) for width-collapsed conv1
    im2col_kernel<<<dim3(6, 8192), 256, 0, stream>>>(vx, ATT, A1);

    // 5) build variant-summed conv1 weights
    wcat_kernel<<<dim3(6, 1536), 256, 0, stream>>>(c1w, WC);

    // 6) Y1 = A1 @ WC^T: M=8192, N=1536, K=1536   (the big one: 38.7 GF)
    gemm_nt<8, false, false><<<dim3(12, 64), 256, 0, stream>>>(
        A1, 1536, 0, WC, 1536, 0, Y1, 1536, 0, nullptr, 0, 1536);

    // 7) maxpool (+conv1 bias) -> P[1024, 2048]
    pool_kernel<<<2048, 256, 0, stream>>>(Y1, c1b, P);

    // 8) fold conv2+mean into M2[512, 2048]
    m2_kernel<<<dim3(8, 512), 256, 0, stream>>>(c2w, M2);

    // 9) out = relu(P @ M2^T + c2b): M=1024, N=512, K=2048
    gemm_nt<4, true, true><<<dim3(8, 16), 256, 0, stream>>>(
        P, 2048, 0, M2, 2048, 0, out, 512, 0, c2b, 0, 2048);
}

// Round 2
// 308.131 us; speedup vs baseline: 2.9119x; 2.9119x over previous
//
#include <hip/hip_runtime.h>
#include <hip/hip_bf16.h>

// B=1024, F=512, N=8
// Restructured pipeline (all heavy math as bf16 MFMA GEMMs, fp32 accumulate):
//  1) X = concat(vx,ax) -> bf16 [1024,1024]
//  2) H = relu(X @ W1^T + b1) -> bf16 [1024,4096]        (8.6 GF)
//  3) ATT = relu(H_n @ W2_n^T + b2_n) -> bf16 [1024,4096] (4.3 GF, batch 8)
//  4) A1 = im2col(vx*ATT) -> bf16 [8192,1536]  (width-collapsed conv1)
//  5) WC = variant-summed conv1 weights -> bf16 [1536,1536]
//  6) Y1 = A1 @ WC^T -> bf16 [8192,1536]                  (38.7 GF)
//  7) P = maxpool+bias -> bf16 [1024,2048]
//  8) M2 = conv2+mean folded -> bf16 [512,2048]
//  9) out = relu(P @ M2^T + c2b) -> fp32 [1024,512]       (2.1 GF)

typedef __attribute__((ext_vector_type(8))) short short8;
typedef __attribute__((ext_vector_type(4))) float f32x4;

__device__ __forceinline__ void gload16(const void* g, void* l) {
    __builtin_amdgcn_global_load_lds(
        (const __attribute__((address_space(1))) void*)g,
        (__attribute__((address_space(3))) void*)l, 16, 0, 0);
}

// ---------------------------------------------------------------------------
// bf16 MFMA GEMM: C[M,N] = A[M,K] * B[N,K]^T, optional bias+relu, batched via z.
// Block = 256 threads (4 waves), tile BM x BN, each wave (BM/2)x(BN/2).
// LDS layout (forced by global_load_lds lane-contiguity, chosen via per-lane
// global addressing): As[kchunk 0..3][row 0..BM-1][8 bf16] — fragment
// ds_read_b128 across lanes 0..15 hits consecutive 16B units => no conflicts.
// MFMA frag layouts (measured, learn_hip m89/m91):
//   A/B operand: elem[m or n = lane&15][k = (lane>>4)*8 + j]
//   C/D:         col  = lane&15, row = (lane>>4)*4 + reg
// ---------------------------------------------------------------------------
template<int BM, int BN, bool RELU, bool BIAS, bool OUT_BF16>
__global__ __launch_bounds__(256) void gemm_mfma(
    const __hip_bfloat16* __restrict__ A, int lda, long sA,
    const __hip_bfloat16* __restrict__ B, int ldb, long sB,
    void* __restrict__ Cv, int ldc, long sC,
    const float* __restrict__ bias, long sBias,
    int K)
{
    constexpr int MI = BM / 32, NI = BN / 32;
    __shared__ __align__(16) __hip_bfloat16 As[4 * BM * 8];
    __shared__ __align__(16) __hip_bfloat16 Bs[4 * BN * 8];
    const int z = blockIdx.z;
    A += (long)z * sA;
    B += (long)z * sB;
    const int bm = blockIdx.y * BM, bn = blockIdx.x * BN;
    const int t = threadIdx.x, lane = t & 63, wid = t >> 6;
    const int q = lane >> 4, lr = lane & 15;
    const int wrow = (wid >> 1) * (BM / 2), wcol = (wid & 1) * (BN / 2);

    f32x4 acc[MI][NI] = {};

    for (int k0 = 0; k0 < K; k0 += 32) {
        if (k0) __syncthreads();
        #pragma unroll
        for (int i = 0; i < BM / 64; ++i) {
            int base = (wid * (BM / 64) + i) * 64;   // wave-uniform
            int l = base + lane;                      // 16B-unit linear index
            int c = l / BM, m = l % BM;               // chunk, row
            gload16(A + (long)(bm + m) * lda + k0 + c * 8, (char*)As + base * 16);
        }
        #pragma unroll
        for (int i = 0; i < BN / 64; ++i) {
            int base = (wid * (BN / 64) + i) * 64;
            int l = base + lane;
            int c = l / BN, n = l % BN;
            gload16(B + (long)(bn + n) * ldb + k0 + c * 8, (char*)Bs + base * 16);
        }
        __syncthreads();

        short8 af[MI], bf[NI];
        #pragma unroll
        for (int mi = 0; mi < MI; ++mi)
            af[mi] = *(const short8*)((const char*)As + (q * BM + wrow + mi * 16 + lr) * 16);
        #pragma unroll
        for (int ni = 0; ni < NI; ++ni)
            bf[ni] = *(const short8*)((const char*)Bs + (q * BN + wcol + ni * 16 + lr) * 16);
        #pragma unroll
        for (int mi = 0; mi < MI; ++mi)
            #pragma unroll
            for (int ni = 0; ni < NI; ++ni)
                acc[mi][ni] = __builtin_amdgcn_mfma_f32_16x16x32_bf16(
                    af[mi], bf[ni], acc[mi][ni], 0, 0, 0);
    }

    #pragma unroll
    for (int mi = 0; mi < MI; ++mi) {
        #pragma unroll
        for (int ni = 0; ni < NI; ++ni) {
            int gn = bn + wcol + ni * 16 + lr;
            float bv = 0.f;
            if constexpr (BIAS) bv = bias[z * sBias + gn];
            #pragma unroll
            for (int r = 0; r < 4; ++r) {
                long gm = bm + wrow + mi * 16 + q * 4 + r;
                float v = acc[mi][ni][r] + bv;
                if constexpr (RELU) v = fmaxf(v, 0.f);
                if constexpr (OUT_BF16)
                    ((__hip_bfloat16*)Cv)[z * sC + gm * ldc + gn] = __float2bfloat16(v);
                else
                    ((float*)Cv)[z * sC + gm * ldc + gn] = v;
            }
        }
    }
}

// x = concat(vx, ax) -> bf16 [1024, 1024]
__global__ void concat_kernel(const float* __restrict__ vx,
                              const float* __restrict__ ax,
                              __hip_bfloat16* __restrict__ x)
{
    int i = blockIdx.x * 256 + threadIdx.x;     // b*512+c
    int b = i >> 9, c = i & 511;
    x[((long)b << 10) + c]       = __float2bfloat16(vx[i]);
    x[((long)b << 10) + 512 + c] = __float2bfloat16(ax[i]);
}

// fp32 -> bf16 cast, 4 elements/thread
__global__ void cast_kernel(const float* __restrict__ in,
                            __hip_bfloat16* __restrict__ out, int n4)
{
    int i = blockIdx.x * 256 + threadIdx.x;
    if (i < n4) {
        float4 v = ((const float4*)in)[i];
        union { __hip_bfloat16 h[4]; short4 s; } u;
        u.h[0] = __float2bfloat16(v.x); u.h[1] = __float2bfloat16(v.y);
        u.h[2] = __float2bfloat16(v.z); u.h[3] = __float2bfloat16(v.w);
        ((short4*)out)[i] = u.s;
    }
}

// A1[(b*8+i)][ki*512+c] = (0<=i+ki-1<8) ? vx[b,c]*att[b,i+ki-1,c] : 0
__global__ void im2col_kernel(const float* __restrict__ vx,
                              const __hip_bfloat16* __restrict__ att,
                              __hip_bfloat16* __restrict__ A1)
{
    int col = blockIdx.x * 256 + threadIdx.x;   // 0..1535
    int row = blockIdx.y;                       // 0..8191 (b*8+i)
    int b = row >> 3, i = row & 7;
    int ki = col >> 9, c = col & 511;
    int ip = i + ki - 1;
    float v = 0.f;
    if (ip >= 0 && ip < 8)
        v = vx[(b << 9) + c] * __bfloat162float(att[((long)b << 12) + (ip << 9) + c]);
    A1[(long)row * 1536 + col] = __float2bfloat16(v);
}

// Wcat[v*512+o][ki*512+c]: v=0 -> kj{1,2}, v=1 -> all kj, v=2 -> kj{0,1}
__global__ void wcat_kernel(const float* __restrict__ w1c,
                            __hip_bfloat16* __restrict__ Wcat)
{
    int col = blockIdx.x * 256 + threadIdx.x;   // ki*512+c
    int row = blockIdx.y;                       // v*512+o
    int v = row >> 9, o = row & 511;
    int ki = col >> 9, c = col & 511;
    const float* w = w1c + ((long)(o * 512 + c) * 3 + ki) * 3;
    float s = w[1];
    if (v != 0) s += w[0];
    if (v != 2) s += w[2];
    Wcat[(long)row * 1536 + col] = __float2bfloat16(s);
}

// maxpool over 8 rows x 3 variants + conv1 bias -> P[b][o*4 + pi*2 + pj] bf16
__global__ void pool_kernel(const __hip_bfloat16* __restrict__ Y1,
                            const float* __restrict__ c1b,
                            __hip_bfloat16* __restrict__ P)
{
    int idx = blockIdx.x * 256 + threadIdx.x;   // b*512+o
    int b = idx >> 9, o = idx & 511;
    const __hip_bfloat16* y = Y1 + (long)b * 8 * 1536 + o;
    float bias = c1b[o];
    float pv[2][2];
    #pragma unroll
    for (int pi = 0; pi < 2; ++pi) {
        float m0 = -3.402823466e38f, m1 = -3.402823466e38f;
        #pragma unroll
        for (int r = 0; r < 4; ++r) {
            int i = pi * 4 + r;
            float yl = __bfloat162float(y[i * 1536 + 0]);
            float ym = __bfloat162float(y[i * 1536 + 512]);
            float yr = __bfloat162float(y[i * 1536 + 1024]);
            m0 = fmaxf(m0, fmaxf(yl, ym));
            m1 = fmaxf(m1, fmaxf(ym, yr));
        }
        pv[pi][0] = m0; pv[pi][1] = m1;
    }
    __hip_bfloat16* pp = P + ((long)b * 2048) + o * 4;
    pp[0] = __float2bfloat16(pv[0][0] + bias);
    pp[1] = __float2bfloat16(pv[0][1] + bias);
    pp[2] = __float2bfloat16(pv[1][0] + bias);
    pp[3] = __float2bfloat16(pv[1][1] + bias);
}

// M2[o2][c*4+pi*2+pj] = 0.25 * sum of 2x2 conv2 taps
__global__ void m2_kernel(const float* __restrict__ w2c,
                          __hip_bfloat16* __restrict__ M2)
{
    int col = blockIdx.x * 256 + threadIdx.x;   // 0..2047
    int o2  = blockIdx.y;                       // 0..511
    int c = col >> 2, pi = (col >> 1) & 1, pj = col & 1;
    const float* w = w2c + (long)(o2 * 512 + c) * 9;
    float s = w[pi * 3 + pj] + w[pi * 3 + pj + 1]
            + w[(pi + 1) * 3 + pj] + w[(pi + 1) * 3 + pj + 1];
    M2[(long)o2 * 2048 + col] = __float2bfloat16(0.25f * s);
}

extern "C" void kernel_launch(void* const* d_in, const int* in_sizes, int n_in,
                              void* d_out, int out_size, void* d_ws, size_t ws_size,
                              hipStream_t stream)
{
    const float* vx  = (const float*)d_in[0];
    const float* ax  = (const float*)d_in[1];
    const float* W1  = (const float*)d_in[2];
    const float* b1  = (const float*)d_in[3];
    const float* W2  = (const float*)d_in[4];
    const float* b2  = (const float*)d_in[5];
    const float* c1w = (const float*)d_in[6];
    const float* c1b = (const float*)d_in[7];
    const float* c2w = (const float*)d_in[8];
    const float* c2b = (const float*)d_in[9];
    float* out = (float*)d_out;
    char* w = (char*)d_ws;

    const long MiB = 1 << 20;
    __hip_bfloat16* Xbf   = (__hip_bfloat16*)(w + 0 * MiB);   // 2 MiB
    __hip_bfloat16* W1bf  = (__hip_bfloat16*)(w + 2 * MiB);   // 8 MiB
    __hip_bfloat16* Hbf   = (__hip_bfloat16*)(w + 10 * MiB);  // 8 MiB
    __hip_bfloat16* W2bf  = (__hip_bfloat16*)(w + 18 * MiB);  // 4 MiB
    __hip_bfloat16* ATTbf = (__hip_bfloat16*)(w + 22 * MiB);  // 8 MiB
    __hip_bfloat16* A1bf  = (__hip_bfloat16*)(w + 30 * MiB);  // 24 MiB
    __hip_bfloat16* WCbf  = (__hip_bfloat16*)(w + 54 * MiB);  // 4.5 MiB
    __hip_bfloat16* Y1bf  = (__hip_bfloat16*)(w + 59 * MiB);  // 24 MiB
    __hip_bfloat16* Pbf   = (__hip_bfloat16*)(w + 83 * MiB);  // 4 MiB
    __hip_bfloat16* M2bf  = (__hip_bfloat16*)(w + 87 * MiB);  // 2 MiB (end 89)

    // 1) concat + weight casts
    concat_kernel<<<2048, 256, 0, stream>>>(vx, ax, Xbf);
    cast_kernel<<<4096, 256, 0, stream>>>(W1, W1bf, 1048576);  // 4M elems
    cast_kernel<<<2048, 256, 0, stream>>>(W2, W2bf, 524288);   // 2M elems

    // 2) H = relu(X @ W1^T + b1): M=1024, N=4096, K=1024
    gemm_mfma<128, 128, true, true, true><<<dim3(32, 8, 1), 256, 0, stream>>>(
        Xbf, 1024, 0, W1bf, 1024, 0, Hbf, 4096, 0, b1, 0, 1024);

    // 3) ATT = relu(H_n @ W2_n^T + b2_n): M=1024, N=512, K=512, batch 8
    gemm_mfma<128, 128, true, true, true><<<dim3(4, 8, 8), 256, 0, stream>>>(
        Hbf, 4096, 512, W2bf, 512, 262144, ATTbf, 4096, 512, b2, 512, 512);

    // 4) im2col, 5) variant-summed conv1 weights
    im2col_kernel<<<dim3(6, 8192), 256, 0, stream>>>(vx, ATTbf, A1bf);
    wcat_kernel<<<dim3(6, 1536), 256, 0, stream>>>(c1w, WCbf);

    // 6) Y1 = A1 @ WC^T: M=8192, N=1536, K=1536 (38.7 GF)
    gemm_mfma<128, 128, false, false, true><<<dim3(12, 64, 1), 256, 0, stream>>>(
        A1bf, 1536, 0, WCbf, 1536, 0, Y1bf, 1536, 0, nullptr, 0, 1536);

    // 7) maxpool(+bias), 8) conv2+mean fold
    pool_kernel<<<2048, 256, 0, stream>>>(Y1bf, c1b, Pbf);
    m2_kernel<<<dim3(8, 512), 256, 0, stream>>>(c2w, M2bf);

    // 9) out = relu(P @ M2^T + c2b): M=1024, N=512, K=2048 (64-tile: 128 blocks)
    gemm_mfma<64, 64, true, true, false><<<dim3(8, 16, 1), 256, 0, stream>>>(
        Pbf, 2048, 0, M2bf, 2048, 0, out, 512, 0, c2b, 0, 2048);
}

// Round 3
// 233.078 us; speedup vs baseline: 3.8496x; 1.3220x over previous
//
#include <hip/hip_runtime.h>
#include <hip/hip_bf16.h>

// B=1024, F=512, N=8 — pipeline:
//  1) X = concat(vx,ax) bf16 [1024,1024]; W1,W2 cast to bf16
//  2) H = relu(X @ W1^T + b1) bf16 [1024,4096]            (8.6 GF)
//  3) ATT = relu(H_n @ W2_n^T + b2_n) bf16, batch 8       (4.3 GF)
//  4) A1 = im2col(vx*ATT) bf16 [8192,1536]  (width-collapsed conv1)
//  5) WC = variant-summed conv1 weights bf16 [1536,1536]
//  6) Y1 = A1 @ WC^T bf16 [8192,1536]                     (38.7 GF)
//  7) P = maxpool+bias bf16 [1024,2048]
//  8) M2 = conv2+mean folded bf16 [512,2048]
//  9) out = relu(P @ M2^T + c2b) fp32 [1024,512]          (2.1 GF)

typedef __attribute__((ext_vector_type(8))) short short8;
typedef __attribute__((ext_vector_type(4))) float f32x4;

__device__ __forceinline__ void gload16(const void* g, void* l) {
    __builtin_amdgcn_global_load_lds(
        (const __attribute__((address_space(1))) void*)g,
        (__attribute__((address_space(3))) void*)l, 16, 0, 0);
}

// ---------------------------------------------------------------------------
// bf16 MFMA GEMM: C[M,N] = A[M,K] * B[N,K]^T, bias+relu optional, batch via z.
// 256 threads (4 waves), tile BM x BN, wave owns (BM/2)x(BN/2), BK=64.
//
// Staging (coalesced + conflict-free): one global_load_lds_dwordx4 covers a
// 16-row x 64B contiguous global region (16 cache lines). Lane lam fetches
// row (lam>>2), k-chunk c = ((lam&3) - (lam>>3)) & 3 (add-rotate swizzle).
// LDS unit index = half*(4*BM) + group*64 + lam  (16B units).
// Fragment read for lane (q=lane>>4, lr=lane&15), k-slice ks, tile mi:
//   unit = ks*(4*BM) + ((wrow>>4)+mi)*64 + lr*4 + ((q + (lr>>1)) & 3)
// -> banks: 16 lanes cover all 32 banks with 2-way aliasing (free minimum).
// MFMA frag maps (measured m89/m91): A/B elem[m|n=lane&15][k=(lane>>4)*8+j];
// C/D col=lane&15, row=(lane>>4)*4+reg.
// ---------------------------------------------------------------------------
template<int BM, int BN, bool RELU, bool BIAS, bool OUT_BF16, bool SWAP>
__global__ __launch_bounds__(256) void gemm_mfma(
    const __hip_bfloat16* __restrict__ A, int lda, long sA,
    const __hip_bfloat16* __restrict__ B, int ldb, long sB,
    void* __restrict__ Cv, int ldc, long sC,
    const float* __restrict__ bias, long sBias,
    int K)
{
    constexpr int MI = BM / 32, NI = BN / 32;
    constexpr int GA = BM / 16, GB = BN / 16;     // 16-row groups per tile
    constexpr int nA = (GA * 2) / 4, nB = (GB * 2) / 4;  // slots per wave
    __shared__ __align__(16) char As[128 * BM];   // 2 halves * 4 chunks * BM * 16B
    __shared__ __align__(16) char Bs[128 * BN];

    const int z = blockIdx.z;
    A += (long)z * sA;
    B += (long)z * sB;
    const int bm = (SWAP ? blockIdx.x : blockIdx.y) * BM;
    const int bn = (SWAP ? blockIdx.y : blockIdx.x) * BN;
    const int t = threadIdx.x, lane = t & 63, wid = t >> 6;
    const int q = lane >> 4, lr = lane & 15;
    const int wrow = (wid >> 1) * (BM / 2), wcol = (wid & 1) * (BN / 2);

    // staging per-lane constants
    const int m_loc = lane >> 2;
    const int cst = ((lane & 3) - (m_loc >> 1)) & 3;   // stored chunk
    const long abase = ((long)(bm + m_loc) * lda + cst * 8) * 2;  // bytes
    const long bbase = ((long)(bn + m_loc) * ldb + cst * 8) * 2;

    // fragment per-lane read offset (units) within a group-block
    const int ro = lr * 4;

    f32x4 acc[MI][NI] = {};

    for (int k0 = 0; k0 < K; k0 += 64) {
        if (k0) __syncthreads();
        #pragma unroll
        for (int i = 0; i < nA; ++i) {
            int s = wid * nA + i, g = s % GA, h = s / GA;
            const char* gp = (const char*)A + abase + ((long)g * 16 * lda + h * 32 + k0) * 2;
            gload16(gp, As + (h * (BM * 4) + g * 64) * 16);
        }
        #pragma unroll
        for (int i = 0; i < nB; ++i) {
            int s = wid * nB + i, g = s % GB, h = s / GB;
            const char* gp = (const char*)B + bbase + ((long)g * 16 * ldb + h * 32 + k0) * 2;
            gload16(gp, Bs + (h * (BN * 4) + g * 64) * 16);
        }
        __syncthreads();

        #pragma unroll
        for (int ks = 0; ks < 2; ++ks) {
            short8 af[MI], bf[NI];
            #pragma unroll
            for (int mi = 0; mi < MI; ++mi) {
                int u = ks * (BM * 4) + ((wrow >> 4) + mi) * 64 + ro + ((q + (lr >> 1)) & 3);
                af[mi] = *(const short8*)(As + u * 16);
            }
            #pragma unroll
            for (int ni = 0; ni < NI; ++ni) {
                int u = ks * (BN * 4) + ((wcol >> 4) + ni) * 64 + ro + ((q + (lr >> 1)) & 3);
                bf[ni] = *(const short8*)(Bs + u * 16);
            }
            #pragma unroll
            for (int mi = 0; mi < MI; ++mi)
                #pragma unroll
                for (int ni = 0; ni < NI; ++ni)
                    acc[mi][ni] = __builtin_amdgcn_mfma_f32_16x16x32_bf16(
                        af[mi], bf[ni], acc[mi][ni], 0, 0, 0);
        }
    }

    #pragma unroll
    for (int mi = 0; mi < MI; ++mi) {
        #pragma unroll
        for (int ni = 0; ni < NI; ++ni) {
            int gn = bn + wcol + ni * 16 + lr;
            float bv = 0.f;
            if constexpr (BIAS) bv = bias[z * sBias + gn];
            #pragma unroll
            for (int r = 0; r < 4; ++r) {
                long gm = bm + wrow + mi * 16 + q * 4 + r;
                float v = acc[mi][ni][r] + bv;
                if constexpr (RELU) v = fmaxf(v, 0.f);
                if constexpr (OUT_BF16)
                    ((__hip_bfloat16*)Cv)[z * sC + gm * ldc + gn] = __float2bfloat16(v);
                else
                    ((float*)Cv)[z * sC + gm * ldc + gn] = v;
            }
        }
    }
}

// x = concat(vx, ax) -> bf16 [1024, 1024]
__global__ void concat_kernel(const float* __restrict__ vx,
                              const float* __restrict__ ax,
                              __hip_bfloat16* __restrict__ x)
{
    int i = blockIdx.x * 256 + threadIdx.x;     // b*512+c
    int b = i >> 9, c = i & 511;
    x[((long)b << 10) + c]       = __float2bfloat16(vx[i]);
    x[((long)b << 10) + 512 + c] = __float2bfloat16(ax[i]);
}

// fp32 -> bf16 cast of W1 (4M elems) then W2 (2M elems), 4 elems/thread
__global__ void cast2_kernel(const float* __restrict__ w1,
                             __hip_bfloat16* __restrict__ o1,
                             const float* __restrict__ w2,
                             __hip_bfloat16* __restrict__ o2)
{
    int i = blockIdx.x * 256 + threadIdx.x;     // 0 .. 1.5M-1 float4 slots
    const float* src = (i < 1048576) ? w1 : w2;
    __hip_bfloat16* dst = (i < 1048576) ? o1 : o2;
    int j = (i < 1048576) ? i : i - 1048576;
    float4 v = ((const float4*)src)[j];
    union { __hip_bfloat16 h[4]; short4 s; } u;
    u.h[0] = __float2bfloat16(v.x); u.h[1] = __float2bfloat16(v.y);
    u.h[2] = __float2bfloat16(v.z); u.h[3] = __float2bfloat16(v.w);
    ((short4*)dst)[j] = u.s;
}

// A1[(b*8+i)][ki*512+c] = (0<=i+ki-1<8) ? vx[b,c]*att[b,i+ki-1,c] : 0
__global__ void im2col_kernel(const float* __restrict__ vx,
                              const __hip_bfloat16* __restrict__ att,
                              __hip_bfloat16* __restrict__ A1)
{
    int col = blockIdx.x * 256 + threadIdx.x;   // 0..1535
    int row = blockIdx.y;                       // 0..8191 (b*8+i)
    int b = row >> 3, i = row & 7;
    int ki = col >> 9, c = col & 511;
    int ip = i + ki - 1;
    float v = 0.f;
    if (ip >= 0 && ip < 8)
        v = vx[(b << 9) + c] * __bfloat162float(att[((long)b << 12) + (ip << 9) + c]);
    A1[(long)row * 1536 + col] = __float2bfloat16(v);
}

// Wcat[v*512+o][ki*512+c]: v=0 -> kj{1,2}, v=1 -> all kj, v=2 -> kj{0,1}
__global__ void wcat_kernel(const float* __restrict__ w1c,
                            __hip_bfloat16* __restrict__ Wcat)
{
    int col = blockIdx.x * 256 + threadIdx.x;   // ki*512+c
    int row = blockIdx.y;                       // v*512+o
    int v = row >> 9, o = row & 511;
    int ki = col >> 9, c = col & 511;
    const float* w = w1c + ((long)(o * 512 + c) * 3 + ki) * 3;
    float s = w[1];
    if (v != 0) s += w[0];
    if (v != 2) s += w[2];
    Wcat[(long)row * 1536 + col] = __float2bfloat16(s);
}

// maxpool over 8 rows x 3 variants + conv1 bias -> P[b][o*4 + pi*2 + pj] bf16
__global__ void pool_kernel(const __hip_bfloat16* __restrict__ Y1,
                            const float* __restrict__ c1b,
                            __hip_bfloat16* __restrict__ P)
{
    int idx = blockIdx.x * 256 + threadIdx.x;   // b*512+o
    int b = idx >> 9, o = idx & 511;
    const __hip_bfloat16* y = Y1 + (long)b * 8 * 1536 + o;
    float bias = c1b[o];
    float pv[2][2];
    #pragma unroll
    for (int pi = 0; pi < 2; ++pi) {
        float m0 = -3.402823466e38f, m1 = -3.402823466e38f;
        #pragma unroll
        for (int r = 0; r < 4; ++r) {
            int i = pi * 4 + r;
            float yl = __bfloat162float(y[i * 1536 + 0]);
            float ym = __bfloat162float(y[i * 1536 + 512]);
            float yr = __bfloat162float(y[i * 1536 + 1024]);
            m0 = fmaxf(m0, fmaxf(yl, ym));
            m1 = fmaxf(m1, fmaxf(ym, yr));
        }
        pv[pi][0] = m0; pv[pi][1] = m1;
    }
    __hip_bfloat16* pp = P + ((long)b * 2048) + o * 4;
    pp[0] = __float2bfloat16(pv[0][0] + bias);
    pp[1] = __float2bfloat16(pv[0][1] + bias);
    pp[2] = __float2bfloat16(pv[1][0] + bias);
    pp[3] = __float2bfloat16(pv[1][1] + bias);
}

// M2[o2][c*4+pi*2+pj] = 0.25 * sum of 2x2 conv2 taps
__global__ void m2_kernel(const float* __restrict__ w2c,
                          __hip_bfloat16* __restrict__ M2)
{
    int col = blockIdx.x * 256 + threadIdx.x;   // 0..2047
    int o2  = blockIdx.y;                       // 0..511
    int c = col >> 2, pi = (col >> 1) & 1, pj = col & 1;
    const float* w = w2c + (long)(o2 * 512 + c) * 9;
    float s = w[pi * 3 + pj] + w[pi * 3 + pj + 1]
            + w[(pi + 1) * 3 + pj] + w[(pi + 1) * 3 + pj + 1];
    M2[(long)o2 * 2048 + col] = __float2bfloat16(0.25f * s);
}

extern "C" void kernel_launch(void* const* d_in, const int* in_sizes, int n_in,
                              void* d_out, int out_size, void* d_ws, size_t ws_size,
                              hipStream_t stream)
{
    const float* vx  = (const float*)d_in[0];
    const float* ax  = (const float*)d_in[1];
    const float* W1  = (const float*)d_in[2];
    const float* b1  = (const float*)d_in[3];
    const float* W2  = (const float*)d_in[4];
    const float* b2  = (const float*)d_in[5];
    const float* c1w = (const float*)d_in[6];
    const float* c1b = (const float*)d_in[7];
    const float* c2w = (const float*)d_in[8];
    const float* c2b = (const float*)d_in[9];
    float* out = (float*)d_out;
    char* w = (char*)d_ws;

    const long MiB = 1 << 20;
    __hip_bfloat16* Xbf   = (__hip_bfloat16*)(w + 0 * MiB);   // 2 MiB
    __hip_bfloat16* W1bf  = (__hip_bfloat16*)(w + 2 * MiB);   // 8 MiB
    __hip_bfloat16* Hbf   = (__hip_bfloat16*)(w + 10 * MiB);  // 8 MiB
    __hip_bfloat16* W2bf  = (__hip_bfloat16*)(w + 18 * MiB);  // 4 MiB
    __hip_bfloat16* ATTbf = (__hip_bfloat16*)(w + 22 * MiB);  // 8 MiB
    __hip_bfloat16* A1bf  = (__hip_bfloat16*)(w + 30 * MiB);  // 24 MiB
    __hip_bfloat16* WCbf  = (__hip_bfloat16*)(w + 54 * MiB);  // 4.5 MiB
    __hip_bfloat16* Y1bf  = (__hip_bfloat16*)(w + 59 * MiB);  // 24 MiB
    __hip_bfloat16* Pbf   = (__hip_bfloat16*)(w + 83 * MiB);  // 4 MiB
    __hip_bfloat16* M2bf  = (__hip_bfloat16*)(w + 87 * MiB);  // 2 MiB (end 89)

    // 1) concat + weight casts
    concat_kernel<<<2048, 256, 0, stream>>>(vx, ax, Xbf);
    cast2_kernel<<<6144, 256, 0, stream>>>(W1, W1bf, W2, W2bf);

    // 2) H = relu(X @ W1^T + b1): M=1024, N=4096, K=1024
    gemm_mfma<128, 128, true, true, true, false><<<dim3(32, 8, 1), 256, 0, stream>>>(
        Xbf, 1024, 0, W1bf, 1024, 0, Hbf, 4096, 0, b1, 0, 1024);

    // 3) ATT = relu(H_n @ W2_n^T + b2_n): M=1024, N=512, K=512, batch 8
    gemm_mfma<128, 128, true, true, true, false><<<dim3(4, 8, 8), 256, 0, stream>>>(
        Hbf, 4096, 512, W2bf, 512, 262144, ATTbf, 4096, 512, b2, 512, 512);

    // 4) im2col, 5) variant-summed conv1 weights
    im2col_kernel<<<dim3(6, 8192), 256, 0, stream>>>(vx, ATTbf, A1bf);
    wcat_kernel<<<dim3(6, 1536), 256, 0, stream>>>(c1w, WCbf);

    // 6) Y1 = A1 @ WC^T: M=8192, N=1536, K=1536 (38.7 GF)
    // SWAP grid: bm on x -> all 12 bn-blocks of a bm-panel share id%8 (XCD)
    gemm_mfma<128, 128, false, false, true, true><<<dim3(64, 12, 1), 256, 0, stream>>>(
        A1bf, 1536, 0, WCbf, 1536, 0, Y1bf, 1536, 0, nullptr, 0, 1536);

    // 7) maxpool(+bias), 8) conv2+mean fold
    pool_kernel<<<2048, 256, 0, stream>>>(Y1bf, c1b, Pbf);
    m2_kernel<<<dim3(8, 512), 256, 0, stream>>>(c2w, M2bf);

    // 9) out = relu(P @ M2^T + c2b): M=1024, N=512, K=2048 (64x64 tiles)
    gemm_mfma<64, 64, true, true, false, false><<<dim3(8, 16, 1), 256, 0, stream>>>(
        Pbf, 2048, 0, M2bf, 2048, 0, out, 512, 0, c2b, 0, 2048);
}

// Round 6
// 223.749 us; speedup vs baseline: 4.0101x; 1.0417x over previous
//
#include <hip/hip_runtime.h>
#include <hip/hip_bf16.h>

// B=1024, F=512, N=8 — pipeline (7 kernel dispatches):
//  1) prep: X=concat(vx,ax) bf16 | W1,W2 cast | WC (variant-summed conv1 w)
//           | M2 (conv2+mean fold)
//  2) H = relu(X @ W1^T + b1) bf16 [1024,4096]            (8.6 GF)
//  3) ATT = relu(H_n @ W2_n^T + b2_n) bf16, batch 8       (4.3 GF)
//  4) A1 = im2col(vx*ATT) bf16 [8192,1536]  (width-collapsed conv1)
//  5) conv gemm: Y = A1 @ WC^T, epilogue max-pools the 4-row window
//     held in each lane's acc regs -> PM[v][b][pi][o] fp32 (38.7 GF)
//  6) combine: cross-variant max + conv1 bias -> P bf16 [1024,2048]
//  7) out = relu(P @ M2^T + c2b) fp32 [1024,512]          (2.1 GF)

typedef __attribute__((ext_vector_type(8))) short short8;
typedef __attribute__((ext_vector_type(4))) float f32x4;

__device__ __forceinline__ void gload16(const void* g, void* l) {
    __builtin_amdgcn_global_load_lds(
        (const __attribute__((address_space(1))) void*)g,
        (__attribute__((address_space(3))) void*)l, 16, 0, 0);
}

// ---------------------------------------------------------------------------
// r3-proven bf16 MFMA GEMM (unchanged): C = A[M,K] * B[N,K]^T (+bias, relu).
// 256 thr (4 waves), tile BM x BN, wave owns (BM/2)x(BN/2), BK=64.
// Staging: coalesced global_load_lds_dwordx4 (16 rows x 64B), add-rotate
// chunk swizzle -> fragment ds_read_b128 at free 2-way bank aliasing.
// MFMA maps (m89/m91): A/B elem[m|n=lane&15][k=(lane>>4)*8+j];
// C/D col=lane&15, row=(lane>>4)*4+r.
// ---------------------------------------------------------------------------
template<int BM, int BN, bool RELU, bool BIAS, bool OUT_BF16, bool SWAP>
__global__ __launch_bounds__(256) void gemm_mfma(
    const __hip_bfloat16* __restrict__ A, int lda, long sA,
    const __hip_bfloat16* __restrict__ B, int ldb, long sB,
    void* __restrict__ Cv, int ldc, long sC,
    const float* __restrict__ bias, long sBias,
    int K)
{
    constexpr int MI = BM / 32, NI = BN / 32;
    constexpr int GA = BM / 16, GB = BN / 16;
    constexpr int nA = (GA * 2) / 4, nB = (GB * 2) / 4;
    __shared__ __align__(16) char As[128 * BM];
    __shared__ __align__(16) char Bs[128 * BN];

    const int z = blockIdx.z;
    A += (long)z * sA;
    B += (long)z * sB;
    const int bm = (SWAP ? blockIdx.x : blockIdx.y) * BM;
    const int bn = (SWAP ? blockIdx.y : blockIdx.x) * BN;
    const int t = threadIdx.x, lane = t & 63, wid = t >> 6;
    const int q = lane >> 4, lr = lane & 15;
    const int wrow = (wid >> 1) * (BM / 2), wcol = (wid & 1) * (BN / 2);

    const int m_loc = lane >> 2;
    const int cst = ((lane & 3) - (m_loc >> 1)) & 3;
    const long abase = ((long)(bm + m_loc) * lda + cst * 8) * 2;
    const long bbase = ((long)(bn + m_loc) * ldb + cst * 8) * 2;
    const int ro = lr * 4;
    const int csel = (lr >> 1);

    f32x4 acc[MI][NI] = {};

    for (int k0 = 0; k0 < K; k0 += 64) {
        if (k0) __syncthreads();
        #pragma unroll
        for (int i = 0; i < nA; ++i) {
            int s = wid * nA + i, g = s % GA, h = s / GA;
            gload16((const char*)A + abase + ((long)g * 16 * lda + h * 32 + k0) * 2,
                    As + (h * (BM * 4) + g * 64) * 16);
        }
        #pragma unroll
        for (int i = 0; i < nB; ++i) {
            int s = wid * nB + i, g = s % GB, h = s / GB;
            gload16((const char*)B + bbase + ((long)g * 16 * ldb + h * 32 + k0) * 2,
                    Bs + (h * (BN * 4) + g * 64) * 16);
        }
        __syncthreads();

        #pragma unroll
        for (int ks = 0; ks < 2; ++ks) {
            short8 af[MI], bf[NI];
            #pragma unroll
            for (int mi = 0; mi < MI; ++mi) {
                int u = ks * (BM * 4) + ((wrow >> 4) + mi) * 64 + ro + ((q + csel) & 3);
                af[mi] = *(const short8*)(As + u * 16);
            }
            #pragma unroll
            for (int ni = 0; ni < NI; ++ni) {
                int u = ks * (BN * 4) + ((wcol >> 4) + ni) * 64 + ro + ((q + csel) & 3);
                bf[ni] = *(const short8*)(Bs + u * 16);
            }
            #pragma unroll
            for (int mi = 0; mi < MI; ++mi)
                #pragma unroll
                for (int ni = 0; ni < NI; ++ni)
                    acc[mi][ni] = __builtin_amdgcn_mfma_f32_16x16x32_bf16(
                        af[mi], bf[ni], acc[mi][ni], 0, 0, 0);
        }
    }

    #pragma unroll
    for (int mi = 0; mi < MI; ++mi) {
        #pragma unroll
        for (int ni = 0; ni < NI; ++ni) {
            int gn = bn + wcol + ni * 16 + lr;
            float bv = 0.f;
            if constexpr (BIAS) bv = bias[z * sBias + gn];
            #pragma unroll
            for (int r = 0; r < 4; ++r) {
                long gm = bm + wrow + mi * 16 + q * 4 + r;
                float v = acc[mi][ni][r] + bv;
                if constexpr (RELU) v = fmaxf(v, 0.f);
                if constexpr (OUT_BF16)
                    ((__hip_bfloat16*)Cv)[z * sC + gm * ldc + gn] = __float2bfloat16(v);
                else
                    ((float*)Cv)[z * sC + gm * ldc + gn] = v;
            }
        }
    }
}

// ---------------------------------------------------------------------------
// Conv GEMM = r3's SWAP gemm body (A=A1 [8192,1536], B=WC [1536,1536], K=1536)
// with the ONLY change in the epilogue: each lane's 4 acc regs are one
// batch's 4-row pool window (rows rowbase+q*4+r, batch=(rowbase>>3)+(q>>1),
// pi=q&1) -> write max to PM[v][b][pi][o] instead of storing Y1.
// ---------------------------------------------------------------------------
__global__ __launch_bounds__(256) void conv_gemm_pool(
    const __hip_bfloat16* __restrict__ A,     // A1 [8192,1536]
    const __hip_bfloat16* __restrict__ B,     // WC [1536,1536]
    float* __restrict__ PM)                   // [3][1024][2][512]
{
    constexpr int BM = 128, BN = 128, MI = 4, NI = 4;
    constexpr int GA = 8, GB = 8, nA = 4, nB = 4;
    const int lda = 1536, ldb = 1536, K = 1536;
    __shared__ __align__(16) char As[128 * BM];
    __shared__ __align__(16) char Bs[128 * BN];

    const int bm = blockIdx.x * BM;           // 64 blocks (bm on x: XCD locality)
    const int bn = blockIdx.y * BN;           // 12 blocks
    const int t = threadIdx.x, lane = t & 63, wid = t >> 6;
    const int q = lane >> 4, lr = lane & 15;
    const int wrow = (wid >> 1) * 64, wcol = (wid & 1) * 64;

    const int m_loc = lane >> 2;
    const int cst = ((lane & 3) - (m_loc >> 1)) & 3;
    const long abase = ((long)(bm + m_loc) * lda + cst * 8) * 2;
    const long bbase = ((long)(bn + m_loc) * ldb + cst * 8) * 2;
    const int ro = lr * 4;
    const int csel = (lr >> 1);

    f32x4 acc[MI][NI] = {};

    for (int k0 = 0; k0 < K; k0 += 64) {
        if (k0) __syncthreads();
        #pragma unroll
        for (int i = 0; i < nA; ++i) {
            int s = wid * nA + i, g = s % GA, h = s / GA;
            gload16((const char*)A + abase + ((long)g * 16 * lda + h * 32 + k0) * 2,
                    As + (h * (BM * 4) + g * 64) * 16);
        }
        #pragma unroll
        for (int i = 0; i < nB; ++i) {
            int s = wid * nB + i, g = s % GB, h = s / GB;
            gload16((const char*)B + bbase + ((long)g * 16 * ldb + h * 32 + k0) * 2,
                    Bs + (h * (BN * 4) + g * 64) * 16);
        }
        __syncthreads();

        #pragma unroll
        for (int ks = 0; ks < 2; ++ks) {
            short8 af[MI], bf[NI];
            #pragma unroll
            for (int mi = 0; mi < MI; ++mi) {
                int u = ks * (BM * 4) + ((wrow >> 4) + mi) * 64 + ro + ((q + csel) & 3);
                af[mi] = *(const short8*)(As + u * 16);
            }
            #pragma unroll
            for (int ni = 0; ni < NI; ++ni) {
                int u = ks * (BN * 4) + ((wcol >> 4) + ni) * 64 + ro + ((q + csel) & 3);
                bf[ni] = *(const short8*)(Bs + u * 16);
            }
            #pragma unroll
            for (int mi = 0; mi < MI; ++mi)
                #pragma unroll
                for (int ni = 0; ni < NI; ++ni)
                    acc[mi][ni] = __builtin_amdgcn_mfma_f32_16x16x32_bf16(
                        af[mi], bf[ni], acc[mi][ni], 0, 0, 0);
        }
    }

    #pragma unroll
    for (int mi = 0; mi < MI; ++mi) {
        int rowbase = bm + wrow + mi * 16;            // multiple of 16
        int batch = (rowbase >> 3) + (q >> 1);
        int pi = q & 1;
        #pragma unroll
        for (int ni = 0; ni < NI; ++ni) {
            int gn = bn + wcol + ni * 16 + lr;
            int v = gn >> 9, o = gn & 511;
            float m = fmaxf(fmaxf(acc[mi][ni][0], acc[mi][ni][1]),
                            fmaxf(acc[mi][ni][2], acc[mi][ni][3]));
            PM[((long)v * 1024 + batch) * 1024 + pi * 512 + o] = m;
        }
    }
}

// A1[(b*8+i)][ki*512+c] = (0<=i+ki-1<8) ? vx[b,c]*att[b,i+ki-1,c] : 0
// (r3-proven; att layout: element (b,n,c) at att[b*4096 + n*512 + c])
__global__ void im2col_kernel(const float* __restrict__ vx,
                              const __hip_bfloat16* __restrict__ att,
                              __hip_bfloat16* __restrict__ A1)
{
    int col = blockIdx.x * 256 + threadIdx.x;   // 0..1535
    int row = blockIdx.y;                       // 0..8191 (b*8+i)
    int b = row >> 3, i = row & 7;
    int ki = col >> 9, c = col & 511;
    int ip = i + ki - 1;
    float v = 0.f;
    if (ip >= 0 && ip < 8)
        v = vx[(b << 9) + c] * __bfloat162float(att[((long)b << 12) + (ip << 9) + c]);
    A1[(long)row * 1536 + col] = __float2bfloat16(v);
}

// ---------------------------------------------------------------------------
// Merged prep: concat X | cast W1 | cast W2 | WC build | M2 build
// ---------------------------------------------------------------------------
__global__ __launch_bounds__(256) void prep_kernel(
    const float* __restrict__ vx, const float* __restrict__ ax,
    const float* __restrict__ W1, const float* __restrict__ W2,
    const float* __restrict__ c1w, const float* __restrict__ c2w,
    __hip_bfloat16* __restrict__ X,  __hip_bfloat16* __restrict__ W1b,
    __hip_bfloat16* __restrict__ W2b, __hip_bfloat16* __restrict__ WC,
    __hip_bfloat16* __restrict__ M2)
{
    int blk = blockIdx.x, t = threadIdx.x;
    if (blk < 2048) {                         // concat: 2048 blocks
        int i = blk * 256 + t, b = i >> 9, c = i & 511;
        X[((long)b << 10) + c]       = __float2bfloat16(vx[i]);
        X[((long)b << 10) + 512 + c] = __float2bfloat16(ax[i]);
    } else if (blk < 8192) {                  // cast W1 (4M) + W2 (2M), float4
        int j = (blk - 2048) * 256 + t;
        const float* src = (j < 1048576) ? W1 : W2;
        __hip_bfloat16* dst = (j < 1048576) ? W1b : W2b;
        int k = (j < 1048576) ? j : j - 1048576;
        float4 v = ((const float4*)src)[k];
        union { __hip_bfloat16 h[4]; short4 s; } u;
        u.h[0] = __float2bfloat16(v.x); u.h[1] = __float2bfloat16(v.y);
        u.h[2] = __float2bfloat16(v.z); u.h[3] = __float2bfloat16(v.w);
        ((short4*)dst)[k] = u.s;
    } else if (blk < 17408) {                 // WC: 9216 blocks
        int b2 = blk - 8192;
        int row = b2 / 6, col = (b2 % 6) * 256 + t;
        int v = row >> 9, o = row & 511;
        int ki = col >> 9, c = col & 511;
        const float* w = c1w + ((long)(o * 512 + c) * 3 + ki) * 3;
        float s = w[1];
        if (v != 0) s += w[0];
        if (v != 2) s += w[2];
        WC[(long)row * 1536 + col] = __float2bfloat16(s);
    } else {                                  // M2: 4096 blocks
        int b2 = blk - 17408;
        int o2 = b2 >> 3, col = (b2 & 7) * 256 + t;
        int c = col >> 2, pi = (col >> 1) & 1, pj = col & 1;
        const float* w = c2w + (long)(o2 * 512 + c) * 9;
        float s = w[pi * 3 + pj] + w[pi * 3 + pj + 1]
                + w[(pi + 1) * 3 + pj] + w[(pi + 1) * 3 + pj + 1];
        M2[(long)o2 * 2048 + col] = __float2bfloat16(0.25f * s);
    }
}

// cross-variant max + conv1 bias -> P[b][o*4 + pi*2 + pj] bf16
__global__ __launch_bounds__(256) void combine_kernel(
    const float* __restrict__ PM, const float* __restrict__ c1b,
    __hip_bfloat16* __restrict__ P)
{
    int idx = blockIdx.x * 256 + threadIdx.x;   // b*512+o
    int b = idx >> 9, o = idx & 511;
    float bias = c1b[o];
    const long vs = 1024L * 1024;
    long base = (long)b * 1024 + o;
    float l0 = PM[base],            l1 = PM[base + 512];
    float m0 = PM[vs + base],       m1 = PM[vs + base + 512];
    float r0 = PM[2 * vs + base],   r1 = PM[2 * vs + base + 512];
    union { __hip_bfloat16 h[4]; short4 s; } u;
    u.h[0] = __float2bfloat16(fmaxf(l0, m0) + bias);
    u.h[1] = __float2bfloat16(fmaxf(m0, r0) + bias);
    u.h[2] = __float2bfloat16(fmaxf(l1, m1) + bias);
    u.h[3] = __float2bfloat16(fmaxf(m1, r1) + bias);
    ((short4*)(P + (long)b * 2048 + o * 4))[0] = u.s;
}

extern "C" void kernel_launch(void* const* d_in, const int* in_sizes, int n_in,
                              void* d_out, int out_size, void* d_ws, size_t ws_size,
                              hipStream_t stream)
{
    const float* vx  = (const float*)d_in[0];
    const float* ax  = (const float*)d_in[1];
    const float* W1  = (const float*)d_in[2];
    const float* b1  = (const float*)d_in[3];
    const float* W2  = (const float*)d_in[4];
    const float* b2  = (const float*)d_in[5];
    const float* c1w = (const float*)d_in[6];
    const float* c1b = (const float*)d_in[7];
    const float* c2w = (const float*)d_in[8];
    const float* c2b = (const float*)d_in[9];
    float* out = (float*)d_out;
    char* w = (char*)d_ws;

    const long MiB = 1 << 20;
    __hip_bfloat16* Xbf   = (__hip_bfloat16*)(w + 0 * MiB);   // 2 MiB
    __hip_bfloat16* W1bf  = (__hip_bfloat16*)(w + 2 * MiB);   // 8 MiB
    __hip_bfloat16* Hbf   = (__hip_bfloat16*)(w + 10 * MiB);  // 8 MiB
    __hip_bfloat16* W2bf  = (__hip_bfloat16*)(w + 18 * MiB);  // 4 MiB
    __hip_bfloat16* ATTbf = (__hip_bfloat16*)(w + 22 * MiB);  // 8 MiB
    __hip_bfloat16* A1bf  = (__hip_bfloat16*)(w + 30 * MiB);  // 24 MiB
    __hip_bfloat16* WCbf  = (__hip_bfloat16*)(w + 54 * MiB);  // 4.5 MiB
    float*          PM    = (float*)         (w + 59 * MiB);  // 12 MiB
    __hip_bfloat16* Pbf   = (__hip_bfloat16*)(w + 71 * MiB);  // 4 MiB
    __hip_bfloat16* M2bf  = (__hip_bfloat16*)(w + 75 * MiB);  // 2 MiB (end 77)

    // 1) merged prep
    prep_kernel<<<21504, 256, 0, stream>>>(vx, ax, W1, W2, c1w, c2w,
                                           Xbf, W1bf, W2bf, WCbf, M2bf);

    // 2) H = relu(X @ W1^T + b1): M=1024, N=4096, K=1024
    gemm_mfma<128, 128, true, true, true, false><<<dim3(32, 8, 1), 256, 0, stream>>>(
        Xbf, 1024, 0, W1bf, 1024, 0, Hbf, 4096, 0, b1, 0, 1024);

    // 3) ATT = relu(H_n @ W2_n^T + b2_n): M=1024, N=512, K=512, batch 8
    gemm_mfma<128, 128, true, true, true, false><<<dim3(4, 8, 8), 256, 0, stream>>>(
        Hbf, 4096, 512, W2bf, 512, 262144, ATTbf, 4096, 512, b2, 512, 512);

    // 4) im2col of va (vx*att) for width-collapsed conv1
    im2col_kernel<<<dim3(6, 8192), 256, 0, stream>>>(vx, ATTbf, A1bf);

    // 5) conv gemm + fused max-pool (38.7 GF)
    conv_gemm_pool<<<dim3(64, 12), 256, 0, stream>>>(A1bf, WCbf, PM);

    // 6) combine variants + bias -> P
    combine_kernel<<<2048, 256, 0, stream>>>(PM, c1b, Pbf);

    // 7) out = relu(P @ M2^T + c2b): M=1024, N=512, K=2048
    gemm_mfma<64, 64, true, true, false, false><<<dim3(8, 16, 1), 256, 0, stream>>>(
        Pbf, 2048, 0, M2bf, 2048, 0, out, 512, 0, c2b, 0, 2048);
}